// Round 2
// baseline (90.766 us; speedup 1.0000x reference)
//
#include <hip/hip_runtime.h>
#include <math.h>

// Poincare contrastive loss, N=4096, D=8, TEMP=0.5.
// sim[i][j] = 1/(1+arcosh(x_ij)), x_ij = 1 + 2*sqdist/((1-sqc_i)(1-sqc_j))
// Rewrite: u = P_i . Q_j  (10-term dot, u = x-1 >= 0 exactly)
//   Q_j = [z_j(8), inv_j, inv_j*raw_j],  inv = 1/(1-min(raw,BOUNDARY))
//   P_i = [-4*inv_i*z_i(8), 2*inv_i*raw_i, 2*inv_i]
// loss = mean_i -(2*sim[i,partner] - log(sum_{j!=i} exp(2*sim[i][j])))
//
// ROUND-16: PWL LUT replaces the trans chain (paid off ~6us).
// ROUND-17 (this round): hoist the column reduce out of the inner loop.
// Per-jp DPP wave-reduce (24 serially-dependent VALU + 2 LDS atomics per jp,
// ~40% of loop issue + a latency chain) -> 32 scalar per-column register
// accumulators (static index via FULL unroll), single batch of 32 mutually
// independent DPP chains at the end (same instr count, perfect ILP, zero
// loop atomics). Non-pair ~53us is fixed cost: 39.5us of it is the harness
// 256MiB workspace poison-fill at 85% HBM (rocprof r1) - untouchable.
//
// SYMMETRY kept: full-matrix row-sum-only variant would double LUT-gather
// traffic on the per-CU LDS pipe (537MB vs 268MB through 78.6TB/s) - worse.

#define D 8
#define QS 12                // padded Q stride (floats) -> 48B, 16B-aligned
#define TWO_N 8192
#define HALF_N 4096
constexpr int BLOCK = 256;
constexpr int JC    = 32;    // j-chunk staged in LDS per block
constexpr int NTILE = 2176;  // sum_{b=0}^{15} (256 - 16b)
constexpr int NSEG  = 368;   // 23 octaves x 16 segments, u in [2^-16, 2^7)
constexpr int SEG_LO = 1776; // (111 << 4): bits>>19 of u = 2^-16
#define BOUNDARY (1.0f - 1e-5f)
#define LN2 0.6931471805599453f

typedef float f32x2 __attribute__((ext_vector_type(2)));

__device__ __forceinline__ float frcp(float x)  { return __builtin_amdgcn_rcpf(x); }
__device__ __forceinline__ float fsqrt(float x) { return __builtin_amdgcn_sqrtf(x); }
__device__ __forceinline__ float flog2(float x) { return __builtin_amdgcn_logf(x); }
__device__ __forceinline__ f32x2 splat(float v) { return (f32x2){v, v}; }

// DPP wave64 sum: result in lane 63.
__device__ __forceinline__ float dpp_wave_sum(float v) {
    int x;
    x = __builtin_amdgcn_update_dpp(0, __float_as_int(v), 0x111, 0xf, 0xf, false); // row_shr:1
    v += __int_as_float(x);
    x = __builtin_amdgcn_update_dpp(0, __float_as_int(v), 0x112, 0xf, 0xf, false); // row_shr:2
    v += __int_as_float(x);
    x = __builtin_amdgcn_update_dpp(0, __float_as_int(v), 0x114, 0xf, 0xe, false); // row_shr:4
    v += __int_as_float(x);
    x = __builtin_amdgcn_update_dpp(0, __float_as_int(v), 0x118, 0xf, 0xc, false); // row_shr:8
    v += __int_as_float(x);
    x = __builtin_amdgcn_update_dpp(0, __float_as_int(v), 0x142, 0xa, 0xf, false); // row_bcast:15
    v += __int_as_float(x);
    x = __builtin_amdgcn_update_dpp(0, __float_as_int(v), 0x143, 0xc, 0xf, false); // row_bcast:31
    v += __int_as_float(x);
    return v;   // lane 63 = full sum
}

// ---- prep: Q[row] = [z(8), inv, inv*raw, 0, 0]; zero denom + out; LUT ----
__global__ __launch_bounds__(256) void prep_kernel(
    const float* __restrict__ zi, const float* __restrict__ zj,
    float* __restrict__ q, float* __restrict__ denom, float* __restrict__ out,
    float2* __restrict__ tab)
{
    const int row = blockIdx.x * 256 + threadIdx.x;
    const float* src = (row < HALF_N) ? (zi + (size_t)row * D)
                                      : (zj + (size_t)(row - HALF_N) * D);
    float4 a = *(const float4*)(src);
    float4 b = *(const float4*)(src + 4);
    float raw = a.x*a.x + a.y*a.y + a.z*a.z + a.w*a.w
              + b.x*b.x + b.y*b.y + b.z*b.z + b.w*b.w;
    float inv = frcp(1.0f - fminf(raw, BOUNDARY));
    float* dst = q + (size_t)row * QS;
    *(float4*)(dst)     = a;
    *(float4*)(dst + 4) = b;
    *(float4*)(dst + 8) = make_float4(inv, inv * raw, 0.0f, 0.0f);
    denom[row] = 0.0f;
    if (row == 0) out[0] = 0.0f;

    // build PWL LUT for g(u) = exp(2/(1+arcosh(1+u))), log2-spaced segments.
    if (row < NSEG) {
        const int m0 = row + SEG_LO;
        const int m1 = m0 + 1;
        float ua_f = __uint_as_float(((unsigned)(m0 >> 4) << 23) | ((unsigned)(m0 & 15) << 19));
        float ub_f = __uint_as_float(((unsigned)(m1 >> 4) << 23) | ((unsigned)(m1 & 15) << 19));
        double ua = (double)ua_f, ub = (double)ub_f;
        double ga = exp(2.0 / (1.0 + log(1.0 + ua + sqrt(ua * (ua + 2.0)))));
        double gb = exp(2.0 / (1.0 + log(1.0 + ub + sqrt(ub * (ub + 2.0)))));
        double sl = (gb - ga) / (ub - ua);
        double ic = ga - sl * ua;
        tab[row] = make_float2((float)sl, (float)ic);
    }
}

// one column's 10-term dot; accumulator starts at 0 so result is u = x-1
__device__ __forceinline__ f32x2 dot_col(const f32x2* __restrict__ p2,
                                         const float* __restrict__ qq)
{
    float4 a  = *(const float4*)(qq);
    float4 bb = *(const float4*)(qq + 4);
    float2 c  = *(const float2*)(qq + 8);
    f32x2 x = splat(0.0f);
    x = __builtin_elementwise_fma(p2[0], splat(a.x),  x);
    x = __builtin_elementwise_fma(p2[1], splat(a.y),  x);
    x = __builtin_elementwise_fma(p2[2], splat(a.z),  x);
    x = __builtin_elementwise_fma(p2[3], splat(a.w),  x);
    x = __builtin_elementwise_fma(p2[4], splat(bb.x), x);
    x = __builtin_elementwise_fma(p2[5], splat(bb.y), x);
    x = __builtin_elementwise_fma(p2[6], splat(bb.z), x);
    x = __builtin_elementwise_fma(p2[7], splat(bb.w), x);
    x = __builtin_elementwise_fma(p2[8], splat(c.x),  x);
    x = __builtin_elementwise_fma(p2[9], splat(c.y),  x);
    return x;
}

// e = exp(2*sim) via PWL table; u must be >= 0
__device__ __forceinline__ float lut1(float u, const float2* __restrict__ tab)
{
    int t = (int)(__float_as_uint(u) >> 19) - SEG_LO;
    t = (t < 0) ? 0 : t;
    t = (t > NSEG - 1) ? NSEG - 1 : t;
    float2 si = tab[t];
    return fmaf(si.x, u, si.y);
}

// ---- symmetric pair kernel: register col-accs, batch DPP reduce at end ----
__global__ __launch_bounds__(BLOCK, 5) void pair_kernel(
    const float* __restrict__ q, const float2* __restrict__ gtab,
    float* __restrict__ denom)
{
    __shared__ alignas(16) float2 stab[NSEG];  // 2.9 KB PWL table
    __shared__ float sq[JC * QS];              // 1.5 KB j-chunk Q
    __shared__ float swave[4][JC];             // per-wave column sums

    const int tid = threadIdx.x;

    // tile decode: t -> (b = i-block of 512 rows, jbase)
    const int t = blockIdx.x;
    int b = 0;
    #pragma unroll
    for (int k = 1; k < 16; ++k)
        b += (t >= (256 * k - 8 * k * (k - 1))) ? 1 : 0;
    const int Fb    = 256 * b - 8 * b * (b - 1);
    const int ibase = 512 * b;
    const int jbase = ibase + 32 * (t - Fb);
    const bool diag = (jbase < ibase + 512);

    // stage LUT (184 float4) + j-chunk Q (96 float4)
    if (tid < NSEG / 2)
        ((float4*)stab)[tid] = ((const float4*)gtab)[tid];
    if (tid < JC * QS / 4)
        ((float4*)sq)[tid] = ((const float4*)(q + (size_t)jbase * QS))[tid];

    // own two rows -> packed P: p2[k] = {P_row0[k], P_row1[k]}
    const int irow0 = ibase + tid;
    const int irow1 = ibase + tid + BLOCK;
    f32x2 p2[10];
    {
        const float* q0 = q + (size_t)irow0 * QS;
        const float* q1 = q + (size_t)irow1 * QS;
        float4 a0 = *(const float4*)(q0), b0 = *(const float4*)(q0 + 4);
        float4 c0 = *(const float4*)(q0 + 8);
        float4 a1 = *(const float4*)(q1), b1 = *(const float4*)(q1 + 4);
        float4 c1 = *(const float4*)(q1 + 8);
        float m0 = -4.0f * c0.x, m1 = -4.0f * c1.x;
        p2[0] = (f32x2){m0 * a0.x, m1 * a1.x};
        p2[1] = (f32x2){m0 * a0.y, m1 * a1.y};
        p2[2] = (f32x2){m0 * a0.z, m1 * a1.z};
        p2[3] = (f32x2){m0 * a0.w, m1 * a1.w};
        p2[4] = (f32x2){m0 * b0.x, m1 * b1.x};
        p2[5] = (f32x2){m0 * b0.y, m1 * b1.y};
        p2[6] = (f32x2){m0 * b0.z, m1 * b1.z};
        p2[7] = (f32x2){m0 * b0.w, m1 * b1.w};
        p2[8] = (f32x2){2.0f * c0.y, 2.0f * c1.y};
        p2[9] = (f32x2){2.0f * c0.x, 2.0f * c1.x};
    }
    f32x2 acc2 = splat(0.0f);
    float colacc[JC];
    #pragma unroll
    for (int c = 0; c < JC; ++c) colacc[c] = 0.0f;

    __syncthreads();

    // FULL unroll: colacc indices must be compile-time constants (VGPR array)
    #pragma unroll
    for (int jp = 0; jp < JC / 2; ++jp) {
        const int jj0 = 2 * jp, jj1 = 2 * jp + 1;

        f32x2 u0 = dot_col(p2, sq + jj0 * QS);
        f32x2 u1 = dot_col(p2, sq + jj1 * QS);
        u0 = __builtin_elementwise_max(u0, splat(0.0f));
        u1 = __builtin_elementwise_max(u1, splat(0.0f));
        f32x2 e0 = (f32x2){lut1(u0.x, stab), lut1(u0.y, stab)};
        f32x2 e1 = (f32x2){lut1(u1.x, stab), lut1(u1.y, stab)};

        if (diag) {
            const int j0 = jbase + jj0, j1 = jbase + jj1;
            e0.x = (j0 > irow0) ? e0.x : 0.0f;
            e0.y = (j0 > irow1) ? e0.y : 0.0f;
            e1.x = (j1 > irow0) ? e1.x : 0.0f;
            e1.y = (j1 > irow1) ? e1.y : 0.0f;
        }
        acc2 += e0;
        acc2 += e1;
        colacc[jj0] += e0.x + e0.y;   // register col accumulators
        colacc[jj1] += e1.x + e1.y;
    }

    // batch column reduce: 32 independent DPP chains (full ILP), once.
    const int wid  = tid >> 6;
    const bool l63 = ((tid & 63) == 63);
    #pragma unroll
    for (int c = 0; c < JC; ++c) {
        float s = dpp_wave_sum(colacc[c]);
        if (l63) swave[wid][c] = s;
    }

    __syncthreads();
    if (tid < JC) {
        float tot = swave[0][tid] + swave[1][tid] + swave[2][tid] + swave[3][tid];
        atomicAdd(&denom[jbase + tid], tot);
    }
    atomicAdd(&denom[irow0], acc2.x);
    atomicAdd(&denom[irow1], acc2.y);
}

// ---- epilogue: 8 blocks x 1024, one row/thread; denom excludes self ----
__global__ __launch_bounds__(1024) void reduce_kernel(
    const float* __restrict__ zi, const float* __restrict__ zj,
    const float* __restrict__ denom, float* __restrict__ out)
{
    __shared__ float s_red[1024];
    const int tid = threadIdx.x;
    const int i   = blockIdx.x * 1024 + tid;

    const int base = (i < HALF_N) ? i : (i - HALF_N);
    const float* pa = (i < HALF_N) ? (zi + (size_t)base * D) : (zj + (size_t)base * D);
    const float* pb = (i < HALF_N) ? (zj + (size_t)base * D) : (zi + (size_t)base * D);
    float4 a0 = *(const float4*)(pa), a1 = *(const float4*)(pa + 4);
    float4 b0 = *(const float4*)(pb), b1 = *(const float4*)(pb + 4);
    float rawa = a0.x*a0.x + a0.y*a0.y + a0.z*a0.z + a0.w*a0.w
               + a1.x*a1.x + a1.y*a1.y + a1.z*a1.z + a1.w*a1.w;
    float rawb = b0.x*b0.x + b0.y*b0.y + b0.z*b0.z + b0.w*b0.w
               + b1.x*b1.x + b1.y*b1.y + b1.z*b1.z + b1.w*b1.w;
    float dot  = a0.x*b0.x + a0.y*b0.y + a0.z*b0.z + a0.w*b0.w
               + a1.x*b1.x + a1.y*b1.y + a1.z*b1.z + a1.w*b1.w;
    float sqd  = fmaxf(rawa + rawb - 2.0f * dot, 0.0f);
    float inva = frcp(1.0f - fminf(rawa, BOUNDARY));
    float invb = frcp(1.0f - fminf(rawb, BOUNDARY));
    float x    = fmaf(2.0f * sqd, inva * invb, 1.0f);
    float t    = fmaf(x, x, -1.0f);
    float s    = fsqrt(fmaxf(t, 0.0f));
    float dist = flog2(x + s) * LN2;
    float sim  = frcp(1.0f + dist);               // positive pair similarity
    float dlog = flog2(denom[i]) * LN2;           // self already excluded
    float term = -(2.0f * sim - dlog);

    s_red[tid] = term;
    __syncthreads();
    for (int off = 512; off > 0; off >>= 1) {
        if (tid < off) s_red[tid] += s_red[tid + off];
        __syncthreads();
    }
    if (tid == 0) atomicAdd(out, s_red[0] * (1.0f / (float)TWO_N));
}

extern "C" void kernel_launch(void* const* d_in, const int* in_sizes, int n_in,
                              void* d_out, int out_size, void* d_ws, size_t ws_size,
                              hipStream_t stream) {
    const float* zi = (const float*)d_in[0];
    const float* zj = (const float*)d_in[1];

    float*  denom = (float*)d_ws;                 // [8192]
    float*  q     = denom + TWO_N;                // [8192 * 12]
    float2* tab   = (float2*)(q + (size_t)TWO_N * QS);  // [368]

    prep_kernel<<<TWO_N / 256, 256, 0, stream>>>(zi, zj, q, denom, (float*)d_out, tab);

    pair_kernel<<<NTILE, BLOCK, 0, stream>>>(q, tab, denom);

    reduce_kernel<<<TWO_N / 1024, 1024, 0, stream>>>(zi, zj, denom, (float*)d_out);
}

// Round 3
// 87.315 us; speedup vs baseline: 1.0395x; 1.0395x over previous
//
#include <hip/hip_runtime.h>
#include <math.h>

// Poincare contrastive loss, N=4096, D=8, TEMP=0.5.
// sim[i][j] = 1/(1+arcosh(x_ij)), x_ij = 1 + 2*sqdist/((1-sqc_i)(1-sqc_j))
// Rewrite: u = P_i . Q_j  (10-term dot, u = x-1 >= 0 exactly)
//   Q_j = [z_j(8), inv_j, inv_j*raw_j],  inv = 1/(1-min(raw,BOUNDARY))
//   P_i = [-4*inv_i*z_i(8), 2*inv_i*raw_i, 2*inv_i]
// loss = mean_i -(2*sim[i,partner] - log(sum_{j!=i} exp(2*sim[i][j])))
//
// ROUND-16: PWL LUT replaces the trans chain (-6us).
// ROUND-17: per-jp DPP reduce -> register colacc + end batch reduce (neutral
//   -> pair is NOT issue-bound; LDS pipe + load-use stalls are the limiter).
// ROUND-18 (this round): Q-column reads off the LDS pipe. The j-chunk Q is
// wave-uniform (blockIdx-derived index) -> read directly from global q; the
// compiler's uniformity analysis emits s_load into SGPRs (constant cache),
// v_pk_fma takes the scalar operand directly. Kills the sq LDS staging and
// its 6 broadcast reads + lgkmcnt stalls per jp (10 -> 4 LDS ops/jp).
// Columns batched in groups of 4 (12 scalar loads, one lgkmcnt(0), then
// gathers count cleanly - SMEM retires OOO so mixing with DS forces
// conservative waits otherwise). LDS now: LUT (2.9KB) + swave only.
// Non-pair ~53us fixed: 39.5us harness 256MiB poison-fill - untouchable.

#define D 8
#define QS 12                // padded Q stride (floats) -> 48B, 16B-aligned
#define TWO_N 8192
#define HALF_N 4096
constexpr int BLOCK = 256;
constexpr int JC    = 32;    // j-chunk per block
constexpr int NTILE = 2176;  // sum_{b=0}^{15} (256 - 16b)
constexpr int NSEG  = 368;   // 23 octaves x 16 segments, u in [2^-16, 2^7)
constexpr int SEG_LO = 1776; // (111 << 4): bits>>19 of u = 2^-16
#define BOUNDARY (1.0f - 1e-5f)
#define LN2 0.6931471805599453f

typedef float f32x2 __attribute__((ext_vector_type(2)));

__device__ __forceinline__ float frcp(float x)  { return __builtin_amdgcn_rcpf(x); }
__device__ __forceinline__ float fsqrt(float x) { return __builtin_amdgcn_sqrtf(x); }
__device__ __forceinline__ float flog2(float x) { return __builtin_amdgcn_logf(x); }
__device__ __forceinline__ f32x2 splat(float v) { return (f32x2){v, v}; }

// DPP wave64 sum: result in lane 63.
__device__ __forceinline__ float dpp_wave_sum(float v) {
    int x;
    x = __builtin_amdgcn_update_dpp(0, __float_as_int(v), 0x111, 0xf, 0xf, false); // row_shr:1
    v += __int_as_float(x);
    x = __builtin_amdgcn_update_dpp(0, __float_as_int(v), 0x112, 0xf, 0xf, false); // row_shr:2
    v += __int_as_float(x);
    x = __builtin_amdgcn_update_dpp(0, __float_as_int(v), 0x114, 0xf, 0xe, false); // row_shr:4
    v += __int_as_float(x);
    x = __builtin_amdgcn_update_dpp(0, __float_as_int(v), 0x118, 0xf, 0xc, false); // row_shr:8
    v += __int_as_float(x);
    x = __builtin_amdgcn_update_dpp(0, __float_as_int(v), 0x142, 0xa, 0xf, false); // row_bcast:15
    v += __int_as_float(x);
    x = __builtin_amdgcn_update_dpp(0, __float_as_int(v), 0x143, 0xc, 0xf, false); // row_bcast:31
    v += __int_as_float(x);
    return v;   // lane 63 = full sum
}

// ---- prep: Q[row] = [z(8), inv, inv*raw, 0, 0]; zero denom + out; LUT ----
__global__ __launch_bounds__(256) void prep_kernel(
    const float* __restrict__ zi, const float* __restrict__ zj,
    float* __restrict__ q, float* __restrict__ denom, float* __restrict__ out,
    float2* __restrict__ tab)
{
    const int row = blockIdx.x * 256 + threadIdx.x;
    const float* src = (row < HALF_N) ? (zi + (size_t)row * D)
                                      : (zj + (size_t)(row - HALF_N) * D);
    float4 a = *(const float4*)(src);
    float4 b = *(const float4*)(src + 4);
    float raw = a.x*a.x + a.y*a.y + a.z*a.z + a.w*a.w
              + b.x*b.x + b.y*b.y + b.z*b.z + b.w*b.w;
    float inv = frcp(1.0f - fminf(raw, BOUNDARY));
    float* dst = q + (size_t)row * QS;
    *(float4*)(dst)     = a;
    *(float4*)(dst + 4) = b;
    *(float4*)(dst + 8) = make_float4(inv, inv * raw, 0.0f, 0.0f);
    denom[row] = 0.0f;
    if (row == 0) out[0] = 0.0f;

    // build PWL LUT for g(u) = exp(2/(1+arcosh(1+u))), log2-spaced segments.
    if (row < NSEG) {
        const int m0 = row + SEG_LO;
        const int m1 = m0 + 1;
        float ua_f = __uint_as_float(((unsigned)(m0 >> 4) << 23) | ((unsigned)(m0 & 15) << 19));
        float ub_f = __uint_as_float(((unsigned)(m1 >> 4) << 23) | ((unsigned)(m1 & 15) << 19));
        double ua = (double)ua_f, ub = (double)ub_f;
        double ga = exp(2.0 / (1.0 + log(1.0 + ua + sqrt(ua * (ua + 2.0)))));
        double gb = exp(2.0 / (1.0 + log(1.0 + ub + sqrt(ub * (ub + 2.0)))));
        double sl = (gb - ga) / (ub - ua);
        double ic = ga - sl * ua;
        tab[row] = make_float2((float)sl, (float)ic);
    }
}

struct QCol { float4 a; float4 b; float2 c; };

// one column's 10-term dot; accumulator starts at 0 so result is u = x-1
__device__ __forceinline__ f32x2 dot_col(const f32x2* __restrict__ p2,
                                         const QCol& qc)
{
    f32x2 x = splat(0.0f);
    x = __builtin_elementwise_fma(p2[0], splat(qc.a.x), x);
    x = __builtin_elementwise_fma(p2[1], splat(qc.a.y), x);
    x = __builtin_elementwise_fma(p2[2], splat(qc.a.z), x);
    x = __builtin_elementwise_fma(p2[3], splat(qc.a.w), x);
    x = __builtin_elementwise_fma(p2[4], splat(qc.b.x), x);
    x = __builtin_elementwise_fma(p2[5], splat(qc.b.y), x);
    x = __builtin_elementwise_fma(p2[6], splat(qc.b.z), x);
    x = __builtin_elementwise_fma(p2[7], splat(qc.b.w), x);
    x = __builtin_elementwise_fma(p2[8], splat(qc.c.x), x);
    x = __builtin_elementwise_fma(p2[9], splat(qc.c.y), x);
    return x;
}

// e = exp(2*sim) via PWL table; u must be >= 0
__device__ __forceinline__ float lut1(float u, const float2* __restrict__ tab)
{
    int t = (int)(__float_as_uint(u) >> 19) - SEG_LO;
    t = (t < 0) ? 0 : t;
    t = (t > NSEG - 1) ? NSEG - 1 : t;
    float2 si = tab[t];
    return fmaf(si.x, u, si.y);
}

// ---- symmetric pair kernel: scalar Q cols, reg col-accs, batch DPP end ----
__global__ __launch_bounds__(BLOCK, 4) void pair_kernel(
    const float* __restrict__ q, const float2* __restrict__ gtab,
    float* __restrict__ denom)
{
    __shared__ alignas(16) float2 stab[NSEG];  // 2.9 KB PWL table
    __shared__ float swave[4][JC];             // per-wave column sums

    const int tid = threadIdx.x;

    // tile decode: t -> (b = i-block of 512 rows, jbase)
    const int t = blockIdx.x;
    int b = 0;
    #pragma unroll
    for (int k = 1; k < 16; ++k)
        b += (t >= (256 * k - 8 * k * (k - 1))) ? 1 : 0;
    const int Fb    = 256 * b - 8 * b * (b - 1);
    const int ibase = 512 * b;
    const int jbase = ibase + 32 * (t - Fb);
    const bool diag = (jbase < ibase + 512);

    // stage LUT (184 float4)
    if (tid < NSEG / 2)
        ((float4*)stab)[tid] = ((const float4*)gtab)[tid];

    // own two rows -> packed P: p2[k] = {P_row0[k], P_row1[k]}
    const int irow0 = ibase + tid;
    const int irow1 = ibase + tid + BLOCK;
    f32x2 p2[10];
    {
        const float* q0 = q + (size_t)irow0 * QS;
        const float* q1 = q + (size_t)irow1 * QS;
        float4 a0 = *(const float4*)(q0), b0 = *(const float4*)(q0 + 4);
        float4 c0 = *(const float4*)(q0 + 8);
        float4 a1 = *(const float4*)(q1), b1 = *(const float4*)(q1 + 4);
        float4 c1 = *(const float4*)(q1 + 8);
        float m0 = -4.0f * c0.x, m1 = -4.0f * c1.x;
        p2[0] = (f32x2){m0 * a0.x, m1 * a1.x};
        p2[1] = (f32x2){m0 * a0.y, m1 * a1.y};
        p2[2] = (f32x2){m0 * a0.z, m1 * a1.z};
        p2[3] = (f32x2){m0 * a0.w, m1 * a1.w};
        p2[4] = (f32x2){m0 * b0.x, m1 * b1.x};
        p2[5] = (f32x2){m0 * b0.y, m1 * b1.y};
        p2[6] = (f32x2){m0 * b0.z, m1 * b1.z};
        p2[7] = (f32x2){m0 * b0.w, m1 * b1.w};
        p2[8] = (f32x2){2.0f * c0.y, 2.0f * c1.y};
        p2[9] = (f32x2){2.0f * c0.x, 2.0f * c1.x};
    }
    f32x2 acc2 = splat(0.0f);
    float colacc[JC];
    #pragma unroll
    for (int c = 0; c < JC; ++c) colacc[c] = 0.0f;

    __syncthreads();   // stab ready

    // 8 groups of 4 columns: batch the (wave-uniform -> s_load) Q-column
    // loads per group, then compute with cleanly-counted DS gathers.
    #pragma unroll
    for (int g = 0; g < JC / 4; ++g) {
        QCol qg[4];
        #pragma unroll
        for (int c = 0; c < 4; ++c) {
            const float* qc = q + (size_t)(jbase + g * 4 + c) * QS;
            qg[c].a = *(const float4*)(qc);
            qg[c].b = *(const float4*)(qc + 4);
            qg[c].c = *(const float2*)(qc + 8);
        }
        #pragma unroll
        for (int cp = 0; cp < 2; ++cp) {
            const int jj0 = g * 4 + 2 * cp, jj1 = jj0 + 1;

            f32x2 u0 = dot_col(p2, qg[2 * cp]);
            f32x2 u1 = dot_col(p2, qg[2 * cp + 1]);
            u0 = __builtin_elementwise_max(u0, splat(0.0f));
            u1 = __builtin_elementwise_max(u1, splat(0.0f));
            f32x2 e0 = (f32x2){lut1(u0.x, stab), lut1(u0.y, stab)};
            f32x2 e1 = (f32x2){lut1(u1.x, stab), lut1(u1.y, stab)};

            if (diag) {
                const int j0 = jbase + jj0, j1 = jbase + jj1;
                e0.x = (j0 > irow0) ? e0.x : 0.0f;
                e0.y = (j0 > irow1) ? e0.y : 0.0f;
                e1.x = (j1 > irow0) ? e1.x : 0.0f;
                e1.y = (j1 > irow1) ? e1.y : 0.0f;
            }
            acc2 += e0;
            acc2 += e1;
            colacc[jj0] += e0.x + e0.y;   // register col accumulators
            colacc[jj1] += e1.x + e1.y;
        }
    }

    // batch column reduce: 32 independent DPP chains (full ILP), once.
    const int wid  = tid >> 6;
    const bool l63 = ((tid & 63) == 63);
    #pragma unroll
    for (int c = 0; c < JC; ++c) {
        float s = dpp_wave_sum(colacc[c]);
        if (l63) swave[wid][c] = s;
    }

    __syncthreads();
    if (tid < JC) {
        float tot = swave[0][tid] + swave[1][tid] + swave[2][tid] + swave[3][tid];
        atomicAdd(&denom[jbase + tid], tot);
    }
    atomicAdd(&denom[irow0], acc2.x);
    atomicAdd(&denom[irow1], acc2.y);
}

// ---- epilogue: 8 blocks x 1024, one row/thread; denom excludes self ----
__global__ __launch_bounds__(1024) void reduce_kernel(
    const float* __restrict__ zi, const float* __restrict__ zj,
    const float* __restrict__ denom, float* __restrict__ out)
{
    __shared__ float s_red[1024];
    const int tid = threadIdx.x;
    const int i   = blockIdx.x * 1024 + tid;

    const int base = (i < HALF_N) ? i : (i - HALF_N);
    const float* pa = (i < HALF_N) ? (zi + (size_t)base * D) : (zj + (size_t)base * D);
    const float* pb = (i < HALF_N) ? (zj + (size_t)base * D) : (zi + (size_t)base * D);
    float4 a0 = *(const float4*)(pa), a1 = *(const float4*)(pa + 4);
    float4 b0 = *(const float4*)(pb), b1 = *(const float4*)(pb + 4);
    float rawa = a0.x*a0.x + a0.y*a0.y + a0.z*a0.z + a0.w*a0.w
               + a1.x*a1.x + a1.y*a1.y + a1.z*a1.z + a1.w*a1.w;
    float rawb = b0.x*b0.x + b0.y*b0.y + b0.z*b0.z + b0.w*b0.w
               + b1.x*b1.x + b1.y*b1.y + b1.z*b1.z + b1.w*b1.w;
    float dot  = a0.x*b0.x + a0.y*b0.y + a0.z*b0.z + a0.w*b0.w
               + a1.x*b1.x + a1.y*b1.y + a1.z*b1.z + a1.w*b1.w;
    float sqd  = fmaxf(rawa + rawb - 2.0f * dot, 0.0f);
    float inva = frcp(1.0f - fminf(rawa, BOUNDARY));
    float invb = frcp(1.0f - fminf(rawb, BOUNDARY));
    float x    = fmaf(2.0f * sqd, inva * invb, 1.0f);
    float t    = fmaf(x, x, -1.0f);
    float s    = fsqrt(fmaxf(t, 0.0f));
    float dist = flog2(x + s) * LN2;
    float sim  = frcp(1.0f + dist);               // positive pair similarity
    float dlog = flog2(denom[i]) * LN2;           // self already excluded
    float term = -(2.0f * sim - dlog);

    s_red[tid] = term;
    __syncthreads();
    for (int off = 512; off > 0; off >>= 1) {
        if (tid < off) s_red[tid] += s_red[tid + off];
        __syncthreads();
    }
    if (tid == 0) atomicAdd(out, s_red[0] * (1.0f / (float)TWO_N));
}

extern "C" void kernel_launch(void* const* d_in, const int* in_sizes, int n_in,
                              void* d_out, int out_size, void* d_ws, size_t ws_size,
                              hipStream_t stream) {
    const float* zi = (const float*)d_in[0];
    const float* zj = (const float*)d_in[1];

    float*  denom = (float*)d_ws;                 // [8192]
    float*  q     = denom + TWO_N;                // [8192 * 12]
    float2* tab   = (float2*)(q + (size_t)TWO_N * QS);  // [368]

    prep_kernel<<<TWO_N / 256, 256, 0, stream>>>(zi, zj, q, denom, (float*)d_out, tab);

    pair_kernel<<<NTILE, BLOCK, 0, stream>>>(q, tab, denom);

    reduce_kernel<<<TWO_N / 1024, 1024, 0, stream>>>(zi, zj, denom, (float*)d_out);
}